// Round 1
// baseline (483.440 us; speedup 1.0000x reference)
//
#include <hip/hip_runtime.h>

// EEG preprocessor: x (B=256, C=128, T=2048) fp32
//   1) subtract channel-mean per (b,t)
//   2) z-score over time per (b,c), std==0 -> divide by 1
//
// One workgroup per batch (grid=256 -> 1 WG/CU), 1024 threads (16 waves).
// Pass 1: mu[t] (mean over channels) into LDS, coalesced float2 loads.
// Pass 2: each wave owns 8 channels; channel data held in registers
//         (float4 v[8] per lane) so output is written without a 3rd read.

#define B 256
#define C 128
#define T 2048

__launch_bounds__(1024, 1)
__global__ void eeg_pre_kernel(const float* __restrict__ x,
                               float* __restrict__ out) {
    const int b = blockIdx.x;
    const size_t base = (size_t)b * (C * T);
    const float* __restrict__ xb = x + base;
    float* __restrict__ ob = out + base;

    __shared__ float mu[T];  // 8 KiB

    const int tid = threadIdx.x;

    // ---- Pass 1: mu[t] = mean over channels, each thread owns t=2*tid, 2*tid+1
    {
        const float2* __restrict__ xb2 = reinterpret_cast<const float2*>(xb);
        float sx = 0.f, sy = 0.f;
        #pragma unroll 8
        for (int c = 0; c < C; ++c) {
            float2 v = xb2[c * (T / 2) + tid];
            sx += v.x;
            sy += v.y;
        }
        const float invC = 1.0f / (float)C;
        reinterpret_cast<float2*>(mu)[tid] = make_float2(sx * invC, sy * invC);
    }
    __syncthreads();

    // ---- Pass 2: per-channel z-score. 16 waves, 8 channels per wave.
    const int wave = tid >> 6;
    const int lane = tid & 63;

    // Hoist mu into registers once per wave (reused across its 8 channels).
    const float4* __restrict__ mu4 = reinterpret_cast<const float4*>(mu);
    float4 mv[8];
    #pragma unroll
    for (int j = 0; j < 8; ++j) mv[j] = mu4[lane + j * 64];

    #pragma unroll 1
    for (int ci = 0; ci < C / 16; ++ci) {
        const int c = wave * (C / 16) + ci;
        const float4* __restrict__ xc4 =
            reinterpret_cast<const float4*>(xb + (size_t)c * T);
        float4* __restrict__ oc4 = reinterpret_cast<float4*>(ob + (size_t)c * T);

        float4 v[8];
        float sum = 0.f, sq = 0.f;
        #pragma unroll
        for (int j = 0; j < 8; ++j) {
            float4 xv = xc4[lane + j * 64];
            float y0 = xv.x - mv[j].x;
            float y1 = xv.y - mv[j].y;
            float y2 = xv.z - mv[j].z;
            float y3 = xv.w - mv[j].w;
            v[j] = make_float4(y0, y1, y2, y3);
            sum += (y0 + y1) + (y2 + y3);
            sq  += ((y0 * y0 + y1 * y1) + (y2 * y2 + y3 * y3));
        }

        // wave64 butterfly reduce
        #pragma unroll
        for (int off = 32; off > 0; off >>= 1) {
            sum += __shfl_down(sum, off, 64);
            sq  += __shfl_down(sq,  off, 64);
        }
        sum = __shfl(sum, 0, 64);
        sq  = __shfl(sq,  0, 64);

        const float invT = 1.0f / (float)T;
        float mean = sum * invT;
        float var = sq * invT - mean * mean;
        var = fmaxf(var, 0.f);
        float sd = sqrtf(var);
        float inv = (sd == 0.f) ? 1.0f : 1.0f / sd;

        #pragma unroll
        for (int j = 0; j < 8; ++j) {
            float4 o;
            o.x = (v[j].x - mean) * inv;
            o.y = (v[j].y - mean) * inv;
            o.z = (v[j].z - mean) * inv;
            o.w = (v[j].w - mean) * inv;
            oc4[lane + j * 64] = o;
        }
    }
}

extern "C" void kernel_launch(void* const* d_in, const int* in_sizes, int n_in,
                              void* d_out, int out_size, void* d_ws, size_t ws_size,
                              hipStream_t stream) {
    const float* x = (const float*)d_in[0];
    float* out = (float*)d_out;
    eeg_pre_kernel<<<B, 1024, 0, stream>>>(x, out);
}

// Round 2
// 478.928 us; speedup vs baseline: 1.0094x; 1.0094x over previous
//
#include <hip/hip_runtime.h>

// EEG preprocessor: x (B=256, C=128, T=2048) fp32
//   1) subtract channel-mean per (b,t)
//   2) z-score over time per (b,c), std==0 -> divide by 1
//
// Two streaming kernels (R1 showed the fused 1-block-per-batch version is
// latency-bound: 2.93 TB/s, occupancy 37%, VALUBusy 6.6%):
//  A) mu[b,t] = mean over channels -> d_ws (2 MiB). grid=2048, fully streaming.
//  B) per-(b,c) z-score, one block per channel, data held in registers.
//     grid=32768 -> deep block queue per CU, no inter-pass barrier coupling.

#define B 256
#define C 128
#define T 2048

__launch_bounds__(256)
__global__ void mu_kernel(const float* __restrict__ x, float* __restrict__ mu) {
    const int b = blockIdx.y;
    const int t0 = blockIdx.x * 256;       // 256 t's per block
    const int tid = threadIdx.x;
    const int wave = tid >> 6;
    const int lane = tid & 63;

    // wave w reduces channels [32w, 32w+32) for t in [t0, t0+256)
    const float4* __restrict__ xp =
        reinterpret_cast<const float4*>(x + ((size_t)b * C + wave * 32) * T + t0);

    float4 acc = make_float4(0.f, 0.f, 0.f, 0.f);
    #pragma unroll 8
    for (int k = 0; k < 32; ++k) {
        float4 v = xp[(size_t)k * (T / 4) + lane];
        acc.x += v.x; acc.y += v.y; acc.z += v.z; acc.w += v.w;
    }

    __shared__ float4 part[4][64];
    part[wave][lane] = acc;
    __syncthreads();

    if (wave == 0) {
        float4 p0 = part[0][lane], p1 = part[1][lane];
        float4 p2 = part[2][lane], p3 = part[3][lane];
        const float invC = 1.0f / (float)C;
        float4 s;
        s.x = (p0.x + p1.x + p2.x + p3.x) * invC;
        s.y = (p0.y + p1.y + p2.y + p3.y) * invC;
        s.z = (p0.z + p1.z + p2.z + p3.z) * invC;
        s.w = (p0.w + p1.w + p2.w + p3.w) * invC;
        reinterpret_cast<float4*>(mu + (size_t)b * T + t0)[lane] = s;
    }
}

__launch_bounds__(256)
__global__ void zscore_kernel(const float* __restrict__ x,
                              const float* __restrict__ mu,
                              float* __restrict__ out) {
    const int bc = blockIdx.x;             // b*C + c
    const int b = bc >> 7;
    const int tid = threadIdx.x;
    const int wave = tid >> 6;
    const int lane = tid & 63;

    const float4* __restrict__ xc = reinterpret_cast<const float4*>(x + (size_t)bc * T);
    const float4* __restrict__ mc = reinterpret_cast<const float4*>(mu + (size_t)b * T);

    float4 v0 = xc[tid];
    float4 v1 = xc[tid + 256];
    float4 m0 = mc[tid];
    float4 m1 = mc[tid + 256];

    float4 y0, y1;
    y0.x = v0.x - m0.x; y0.y = v0.y - m0.y; y0.z = v0.z - m0.z; y0.w = v0.w - m0.w;
    y1.x = v1.x - m1.x; y1.y = v1.y - m1.y; y1.z = v1.z - m1.z; y1.w = v1.w - m1.w;

    float sum = ((y0.x + y0.y) + (y0.z + y0.w)) + ((y1.x + y1.y) + (y1.z + y1.w));
    float sq  = ((y0.x * y0.x + y0.y * y0.y) + (y0.z * y0.z + y0.w * y0.w))
              + ((y1.x * y1.x + y1.y * y1.y) + (y1.z * y1.z + y1.w * y1.w));

    // wave64 butterfly: every lane ends with the wave total
    #pragma unroll
    for (int off = 32; off > 0; off >>= 1) {
        sum += __shfl_xor(sum, off, 64);
        sq  += __shfl_xor(sq,  off, 64);
    }

    __shared__ float2 wsum[4];
    if (lane == 0) wsum[wave] = make_float2(sum, sq);
    __syncthreads();

    float2 a0 = wsum[0], a1 = wsum[1], a2 = wsum[2], a3 = wsum[3];
    float tsum = (a0.x + a1.x) + (a2.x + a3.x);
    float tsq  = (a0.y + a1.y) + (a2.y + a3.y);

    const float invT = 1.0f / (float)T;
    float mean = tsum * invT;
    float var = tsq * invT - mean * mean;
    var = fmaxf(var, 0.f);
    float sd = sqrtf(var);
    float inv = (sd == 0.f) ? 1.0f : 1.0f / sd;

    float4* __restrict__ oc = reinterpret_cast<float4*>(out + (size_t)bc * T);
    float4 o0, o1;
    o0.x = (y0.x - mean) * inv; o0.y = (y0.y - mean) * inv;
    o0.z = (y0.z - mean) * inv; o0.w = (y0.w - mean) * inv;
    o1.x = (y1.x - mean) * inv; o1.y = (y1.y - mean) * inv;
    o1.z = (y1.z - mean) * inv; o1.w = (y1.w - mean) * inv;
    oc[tid] = o0;
    oc[tid + 256] = o1;
}

extern "C" void kernel_launch(void* const* d_in, const int* in_sizes, int n_in,
                              void* d_out, int out_size, void* d_ws, size_t ws_size,
                              hipStream_t stream) {
    const float* x = (const float*)d_in[0];
    float* out = (float*)d_out;
    float* mu = (float*)d_ws;  // B*T floats = 2 MiB

    dim3 gridA(T / 256, B);
    mu_kernel<<<gridA, 256, 0, stream>>>(x, mu);
    zscore_kernel<<<B * C, 256, 0, stream>>>(x, mu, out);
}